// Round 13
// baseline (283.712 us; speedup 1.0000x reference)
//
#include <hip/hip_runtime.h>
#include <math.h>

#define NB   16
#define NN   307
#define MPAD 308          // padded m for G rows
#define Q4   77           // MPAD/4: m-tiles of 4
#define KCH  3
#define IND  66           // INPUT_DIM + HIDDEN
#define KI   198          // KCH * IND
#define HID  64
#define HG   128          // 2 * HIDDEN

typedef float f32x4 __attribute__((ext_vector_type(4)));

// ws layout (floats)
#define OFF_GP   0
#define SZ_GP    (KCH * NN * MPAD)        // 283,668
#define OFF_X1   (OFF_GP + SZ_GP)
#define SZ_X     (NB * Q4 * IND * 4)      // 325,248  x tiled: [b][q][i][e], m = 4q+e
#define OFF_X2   (OFF_X1 + SZ_X)
#define OFF_Z    (OFF_X2 + SZ_X)
#define SZ_Z     (NB * NN * HID)          // 314,368
#define OFF_DZ   (OFF_Z + SZ_Z)           // probe dummies
#define OFF_DX2  (OFF_DZ + SZ_Z)
#define OFF_DOUT (OFF_DX2 + SZ_X)
#define SZ_X2I   (NB * Q4 * 2 * 4)        // x2 xt-row init elements (i<2 only)

__global__ void prep_kernel(const float* __restrict__ G,
                            const float* __restrict__ xt,
                            const float* __restrict__ h,
                            float* __restrict__ G_p,
                            float* __restrict__ x1,
                            float* __restrict__ x2) {
    int idx = blockIdx.x * blockDim.x + threadIdx.x;
    if (idx < SZ_GP) {
        int mp = idx % MPAD;
        int kn = idx / MPAD;
        G_p[idx] = (mp < NN) ? G[kn * NN + mp] : 0.f;
    } else if (idx < SZ_GP + SZ_X) {
        int j = idx - SZ_GP;
        int e = j & 3;
        int t = j >> 2;
        int i = t % IND;
        int q = (t / IND) % Q4;
        int b = t / (IND * Q4);
        int m = q * 4 + e;
        float v = 0.f;
        if (m < NN)
            v = (i < 2) ? xt[(b * NN + m) * 2 + i]
                        : h[(b * NN + m) * HID + (i - 2)];
        x1[j] = v;
    } else if (idx < SZ_GP + SZ_X + SZ_X2I) {
        int j = idx - SZ_GP - SZ_X;
        int e  = j & 3;
        int t  = j >> 2;
        int i  = t & 1;
        int t2 = t >> 1;
        int q  = t2 % Q4;
        int b  = t2 / Q4;
        int m  = q * 4 + e;
        float v = (m < NN) ? xt[(b * NN + m) * 2 + i] : 0.f;
        x2[(((size_t)b * Q4 + q) * IND + i) * 4 + e] = v;
    }
}

// K1: fused gcn1 + gate. P1=0 -> stream-only probe (s zeroed).
template<int P1>
__global__ __launch_bounds__(128) void gate_fused(const float* __restrict__ G_p,
                                                  const float* __restrict__ xT,
                                                  const float* __restrict__ W,
                                                  const float* __restrict__ bias,
                                                  const float* __restrict__ h,
                                                  float* __restrict__ z_out,
                                                  float* __restrict__ xT2) {
    __shared__ float s[KI];
    __shared__ float red[4][HG];
    const int bn  = blockIdx.x;
    const int b   = bn / NN;
    const int n   = bn % NN;
    const int tid = threadIdx.x;
    if (P1) {
        if (tid < IND) {
            const f32x4* xp = (const f32x4*)xT + (size_t)b * (Q4 * IND) + tid;
            const f32x4* gp = (const f32x4*)G_p + (size_t)n * Q4;
            f32x4 a0 = {0.f, 0.f, 0.f, 0.f}, a1 = a0, a2 = a0;
            #pragma unroll 7
            for (int q = 0; q < Q4; ++q) {
                f32x4 xv = xp[(size_t)q * IND];       // coalesced across lanes
                a0 += xv * gp[q];                      // wave-uniform broadcasts
                a1 += xv * gp[q + (size_t)NN * Q4];
                a2 += xv * gp[q + (size_t)2 * NN * Q4];
            }
            s[tid]           = a0.x + a0.y + a0.z + a0.w;
            s[IND + tid]     = a1.x + a1.y + a1.z + a1.w;
            s[2 * IND + tid] = a2.x + a2.y + a2.z + a2.w;
        }
    } else {
        for (int t = tid; t < KI; t += 128) s[t] = 0.f;
    }
    __syncthreads();
    // ---- phase 2: W stream ----
    const int r  = tid >> 5;
    const int c4 = (tid & 31) * 4;
    const f32x4* Wp = (const f32x4*)(W + (size_t)bn * KI * HG + c4);
    float4 acc = make_float4(0.f, 0.f, 0.f, 0.f);
    #pragma unroll 8
    for (int i = r; i < KI; i += 4) {
        f32x4 w = __builtin_nontemporal_load(Wp + (size_t)i * (HG / 4));
        float sv = s[i];
        acc.x += sv * w.x; acc.y += sv * w.y;
        acc.z += sv * w.z; acc.w += sv * w.w;
    }
    red[r][c4 + 0] = acc.x; red[r][c4 + 1] = acc.y;
    red[r][c4 + 2] = acc.z; red[r][c4 + 3] = acc.w;
    __syncthreads();
    float a = bias[bn * HG + tid] + red[0][tid] + red[1][tid] + red[2][tid] + red[3][tid];
    float g = 1.0f / (1.0f + expf(-a));
    if (tid < HID) {
        z_out[bn * HID + tid] = g;                    // z
    } else {
        int hh = tid - HID;                           // r gate -> candidate elem at m=n
        int q = n >> 2, e = n & 3;
        xT2[(((size_t)b * Q4 + q) * IND + 2 + hh) * 4 + e] = g * h[bn * HID + hh];
    }
}

// K2: fused gcn2 + update. P1=0 -> stream-only probe.
template<int P1>
__global__ __launch_bounds__(128) void update_fused(const float* __restrict__ G_p,
                                                    const float* __restrict__ xT2,
                                                    const float* __restrict__ W,
                                                    const float* __restrict__ bias,
                                                    const float* __restrict__ z,
                                                    const float* __restrict__ h,
                                                    float* __restrict__ out) {
    __shared__ float s[KI];
    __shared__ float red[8][HID];
    const int bn  = blockIdx.x;
    const int b   = bn / NN;
    const int n   = bn % NN;
    const int tid = threadIdx.x;
    if (P1) {
        if (tid < IND) {
            const f32x4* xp = (const f32x4*)xT2 + (size_t)b * (Q4 * IND) + tid;
            const f32x4* gp = (const f32x4*)G_p + (size_t)n * Q4;
            f32x4 a0 = {0.f, 0.f, 0.f, 0.f}, a1 = a0, a2 = a0;
            #pragma unroll 7
            for (int q = 0; q < Q4; ++q) {
                f32x4 xv = xp[(size_t)q * IND];
                a0 += xv * gp[q];
                a1 += xv * gp[q + (size_t)NN * Q4];
                a2 += xv * gp[q + (size_t)2 * NN * Q4];
            }
            s[tid]           = a0.x + a0.y + a0.z + a0.w;
            s[IND + tid]     = a1.x + a1.y + a1.z + a1.w;
            s[2 * IND + tid] = a2.x + a2.y + a2.z + a2.w;
        }
    } else {
        for (int t = tid; t < KI; t += 128) s[t] = 0.f;
    }
    __syncthreads();
    // ---- phase 2 ----
    const int r  = tid >> 4;
    const int c4 = (tid & 15) * 4;
    const f32x4* Wp = (const f32x4*)(W + (size_t)bn * KI * HID + c4);
    float4 acc = make_float4(0.f, 0.f, 0.f, 0.f);
    #pragma unroll 8
    for (int i = r; i < KI; i += 8) {
        f32x4 w = __builtin_nontemporal_load(Wp + (size_t)i * (HID / 4));
        float sv = s[i];
        acc.x += sv * w.x; acc.y += sv * w.y;
        acc.z += sv * w.z; acc.w += sv * w.w;
    }
    red[r][c4 + 0] = acc.x; red[r][c4 + 1] = acc.y;
    red[r][c4 + 2] = acc.z; red[r][c4 + 3] = acc.w;
    __syncthreads();
    if (tid < HID) {
        float a = bias[bn * HID + tid];
        #pragma unroll
        for (int rr = 0; rr < 8; ++rr) a += red[rr][tid];
        float nn = tanhf(a);
        float zz = z[bn * HID + tid];
        float hv = h[bn * HID + tid];
        out[bn * HID + tid] = zz * nn + (1.f - zz) * hv;
    }
}

extern "C" void kernel_launch(void* const* d_in, const int* in_sizes, int n_in,
                              void* d_out, int out_size, void* d_ws, size_t ws_size,
                              hipStream_t stream) {
    const float* G  = (const float*)d_in[0];
    const float* xt = (const float*)d_in[1];
    const float* h  = (const float*)d_in[2];
    const float* Wg = (const float*)d_in[3];
    const float* bg = (const float*)d_in[4];
    const float* Wu = (const float*)d_in[5];
    const float* bu = (const float*)d_in[6];
    float* out = (float*)d_out;

    float* ws   = (float*)d_ws;
    float* G_p  = ws + OFF_GP;
    float* x1   = ws + OFF_X1;
    float* x2   = ws + OFF_X2;
    float* z    = ws + OFF_Z;
    float* dz   = ws + OFF_DZ;    // probe-only dead outputs
    float* dx2  = ws + OFF_DX2;
    float* dout = ws + OFF_DOUT;

    const int totPrep = SZ_GP + SZ_X + SZ_X2I;
    prep_kernel<<<(totPrep + 255) / 256, 256, 0, stream>>>(G, xt, h, G_p, x1, x2);

    gate_fused<1><<<NB * NN, 128, 0, stream>>>(G_p, x1, Wg, bg, h, z, x2);

    update_fused<1><<<NB * NN, 128, 0, stream>>>(G_p, x2, Wu, bu, z, h, out);

    // ---- stream-only probes (outputs to dead ws scratch; same Wg->Wu order
    //      as R5 so L3-cold bias matches the 117-us reference) ----
    gate_fused<0><<<NB * NN, 128, 0, stream>>>(G_p, x1, Wg, bg, h, dz, dx2);

    update_fused<0><<<NB * NN, 128, 0, stream>>>(G_p, x2, Wu, bu, z, h, dout);
}

// Round 14
// 170.302 us; speedup vs baseline: 1.6659x; 1.6659x over previous
//
#include <hip/hip_runtime.h>
#include <math.h>

#define NB   16
#define NN   307
#define MPAD 308          // padded m for G rows
#define Q4   77           // MPAD/4: m-tiles of 4
#define KCH  3
#define IND  66           // INPUT_DIM + HIDDEN
#define KI   198          // KCH * IND
#define HID  64
#define HG   128          // 2 * HIDDEN
#define NPAIR 154         // ceil(307/2)

typedef float f32x4 __attribute__((ext_vector_type(4)));

// ws layout (floats)
#define OFF_GP   0
#define SZ_GP    (KCH * NN * MPAD)        // 283,668
#define OFF_X1   (OFF_GP + SZ_GP)
#define SZ_X     (NB * Q4 * IND * 4)      // 325,248  x tiled: [b][q][i][e], m = 4q+e
#define OFF_X2   (OFF_X1 + SZ_X)
#define OFF_Z    (OFF_X2 + SZ_X)
#define SZ_X2I   (NB * Q4 * 2 * 4)        // x2 xt-row init elements (i<2 only)

__global__ void prep_kernel(const float* __restrict__ G,
                            const float* __restrict__ xt,
                            const float* __restrict__ h,
                            float* __restrict__ G_p,
                            float* __restrict__ x1,
                            float* __restrict__ x2) {
    int idx = blockIdx.x * blockDim.x + threadIdx.x;
    if (idx < SZ_GP) {
        int mp = idx % MPAD;
        int kn = idx / MPAD;
        G_p[idx] = (mp < NN) ? G[kn * NN + mp] : 0.f;
    } else if (idx < SZ_GP + SZ_X) {
        int j = idx - SZ_GP;
        int e = j & 3;
        int t = j >> 2;
        int i = t % IND;
        int q = (t / IND) % Q4;
        int b = t / (IND * Q4);
        int m = q * 4 + e;
        float v = 0.f;
        if (m < NN)
            v = (i < 2) ? xt[(b * NN + m) * 2 + i]
                        : h[(b * NN + m) * HID + (i - 2)];
        x1[j] = v;
    } else if (idx < SZ_GP + SZ_X + SZ_X2I) {
        int j = idx - SZ_GP - SZ_X;
        int e  = j & 3;
        int t  = j >> 2;
        int i  = t & 1;
        int t2 = t >> 1;
        int q  = t2 % Q4;
        int b  = t2 / Q4;
        int m  = q * 4 + e;
        float v = (m < NN) ? xt[(b * NN + m) * 2 + i] : 0.f;
        x2[(((size_t)b * Q4 + q) * IND + i) * 4 + e] = v;
    }
}

// ---- dual-n phase-1: lanes 0..65 compute sup rows for na and nb sharing xv ----
__device__ __forceinline__ void phase1_dual(const f32x4* __restrict__ G4,
                                            const f32x4* __restrict__ X4,
                                            int b, int na, int nbc, int tid,
                                            float s[2][KI]) {
    if (tid < IND) {
        const f32x4* xp  = X4 + (size_t)b * (Q4 * IND) + tid;
        const f32x4* gA0 = G4 + ((size_t)0 * NN + na) * Q4;
        const f32x4* gA1 = G4 + ((size_t)1 * NN + na) * Q4;
        const f32x4* gA2 = G4 + ((size_t)2 * NN + na) * Q4;
        const f32x4* gB0 = G4 + ((size_t)0 * NN + nbc) * Q4;
        const f32x4* gB1 = G4 + ((size_t)1 * NN + nbc) * Q4;
        const f32x4* gB2 = G4 + ((size_t)2 * NN + nbc) * Q4;
        f32x4 aA0 = {0.f,0.f,0.f,0.f}, aA1 = aA0, aA2 = aA0;
        f32x4 aB0 = aA0, aB1 = aA0, aB2 = aA0;
        #pragma unroll 4
        for (int q = 0; q < Q4; ++q) {
            f32x4 xv = xp[(size_t)q * IND];   // coalesced; shared by both panels
            aA0 += xv * gA0[q];  aA1 += xv * gA1[q];  aA2 += xv * gA2[q];
            aB0 += xv * gB0[q];  aB1 += xv * gB1[q];  aB2 += xv * gB2[q];
        }
        s[0][tid]           = aA0.x + aA0.y + aA0.z + aA0.w;
        s[0][IND + tid]     = aA1.x + aA1.y + aA1.z + aA1.w;
        s[0][2 * IND + tid] = aA2.x + aA2.y + aA2.z + aA2.w;
        s[1][tid]           = aB0.x + aB0.y + aB0.z + aB0.w;
        s[1][IND + tid]     = aB1.x + aB1.y + aB1.z + aB1.w;
        s[1][2 * IND + tid] = aB2.x + aB2.y + aB2.z + aB2.w;
    }
    __syncthreads();
}

// K1: fused gcn1 + gate, dual-n blocks (256 thr).
__global__ __launch_bounds__(256) void gate_fused(const float* __restrict__ G_p,
                                                  const float* __restrict__ xT,
                                                  const float* __restrict__ W,
                                                  const float* __restrict__ bias,
                                                  const float* __restrict__ h,
                                                  float* __restrict__ z_out,
                                                  float* __restrict__ xT2) {
    __shared__ float s[2][KI];
    __shared__ float red[2][4][HG];
    const int blk = blockIdx.x;
    const int b   = blk / NPAIR;
    const int na  = (blk % NPAIR) * 2;
    const int nb  = na + 1;
    const int nbc = (nb < NN) ? nb : (NN - 1);
    const int tid = threadIdx.x;
    phase1_dual((const f32x4*)G_p, (const f32x4*)xT, b, na, nbc, tid, s);
    // ---- phase 2: each 128-thread group streams its panel ----
    const int p   = tid >> 7;           // panel
    const int t   = tid & 127;
    const int n   = na + p;
    const int bnc = b * NN + ((n < NN) ? n : (NN - 1));
    const int r   = t >> 5;
    const int c4  = (t & 31) * 4;
    const f32x4* Wp = (const f32x4*)(W + (size_t)bnc * KI * HG + c4);
    const float* sp = s[p];
    float4 acc = make_float4(0.f, 0.f, 0.f, 0.f);
    #pragma unroll 8
    for (int i = r; i < KI; i += 4) {
        f32x4 w = __builtin_nontemporal_load(Wp + (size_t)i * (HG / 4));
        float sv = sp[i];
        acc.x += sv * w.x; acc.y += sv * w.y;
        acc.z += sv * w.z; acc.w += sv * w.w;
    }
    red[p][r][c4 + 0] = acc.x; red[p][r][c4 + 1] = acc.y;
    red[p][r][c4 + 2] = acc.z; red[p][r][c4 + 3] = acc.w;
    __syncthreads();
    float a = bias[(size_t)bnc * HG + t]
            + red[p][0][t] + red[p][1][t] + red[p][2][t] + red[p][3][t];
    float g = 1.0f / (1.0f + expf(-a));
    if (n < NN) {
        const int bn = b * NN + n;
        if (t < HID) {
            z_out[bn * HID + t] = g;                  // z
        } else {
            int hh = t - HID;                         // r gate -> cand elem at m=n
            int q = n >> 2, e = n & 3;
            xT2[(((size_t)b * Q4 + q) * IND + 2 + hh) * 4 + e] = g * h[bn * HID + hh];
        }
    }
}

// K2: fused gcn2 + update, dual-n blocks (256 thr).
__global__ __launch_bounds__(256) void update_fused(const float* __restrict__ G_p,
                                                    const float* __restrict__ xT2,
                                                    const float* __restrict__ W,
                                                    const float* __restrict__ bias,
                                                    const float* __restrict__ z,
                                                    const float* __restrict__ h,
                                                    float* __restrict__ out) {
    __shared__ float s[2][KI];
    __shared__ float red[2][8][HID];
    const int blk = blockIdx.x;
    const int b   = blk / NPAIR;
    const int na  = (blk % NPAIR) * 2;
    const int nb  = na + 1;
    const int nbc = (nb < NN) ? nb : (NN - 1);
    const int tid = threadIdx.x;
    phase1_dual((const f32x4*)G_p, (const f32x4*)xT2, b, na, nbc, tid, s);
    // ---- phase 2 ----
    const int p   = tid >> 7;
    const int t   = tid & 127;
    const int n   = na + p;
    const int bnc = b * NN + ((n < NN) ? n : (NN - 1));
    const int r   = t >> 4;
    const int c4  = (t & 15) * 4;
    const f32x4* Wp = (const f32x4*)(W + (size_t)bnc * KI * HID + c4);
    const float* sp = s[p];
    float4 acc = make_float4(0.f, 0.f, 0.f, 0.f);
    #pragma unroll 8
    for (int i = r; i < KI; i += 8) {
        f32x4 w = __builtin_nontemporal_load(Wp + (size_t)i * (HID / 4));
        float sv = sp[i];
        acc.x += sv * w.x; acc.y += sv * w.y;
        acc.z += sv * w.z; acc.w += sv * w.w;
    }
    red[p][r][c4 + 0] = acc.x; red[p][r][c4 + 1] = acc.y;
    red[p][r][c4 + 2] = acc.z; red[p][r][c4 + 3] = acc.w;
    __syncthreads();
    if (t < HID && n < NN) {
        const int bn = b * NN + n;
        float a = bias[(size_t)bnc * HID + t];
        #pragma unroll
        for (int rr = 0; rr < 8; ++rr) a += red[p][rr][t];
        float nn = tanhf(a);
        float zz = z[bn * HID + t];
        float hv = h[bn * HID + t];
        out[bn * HID + t] = zz * nn + (1.f - zz) * hv;
    }
}

extern "C" void kernel_launch(void* const* d_in, const int* in_sizes, int n_in,
                              void* d_out, int out_size, void* d_ws, size_t ws_size,
                              hipStream_t stream) {
    const float* G  = (const float*)d_in[0];
    const float* xt = (const float*)d_in[1];
    const float* h  = (const float*)d_in[2];
    const float* Wg = (const float*)d_in[3];
    const float* bg = (const float*)d_in[4];
    const float* Wu = (const float*)d_in[5];
    const float* bu = (const float*)d_in[6];
    float* out = (float*)d_out;

    float* ws   = (float*)d_ws;
    float* G_p  = ws + OFF_GP;
    float* x1   = ws + OFF_X1;
    float* x2   = ws + OFF_X2;
    float* z    = ws + OFF_Z;

    const int totPrep = SZ_GP + SZ_X + SZ_X2I;
    prep_kernel<<<(totPrep + 255) / 256, 256, 0, stream>>>(G, xt, h, G_p, x1, x2);

    gate_fused<<<NB * NPAIR, 256, 0, stream>>>(G_p, x1, Wg, bg, h, z, x2);

    update_fused<<<NB * NPAIR, 256, 0, stream>>>(G_p, x2, Wu, bu, z, h, out);
}